// Round 6
// baseline (757.593 us; speedup 1.0000x reference)
//
#include <hip/hip_runtime.h>

// LSTM: B=2048, T=512, I=1, H=64, L=2, O=1. fp32 in/out.
// Round 18: DECISIVE EXPERIMENT - 2 independent blocks per CU (BT=4).
//   r14/r16/r17: MfmaUtil+VALUBusy ~= 98% across three geometries; cycle
//   model fits step=1922cy as matrix(734)+trans(~450)+valu(~600)+lds/bar
//   (~150) fully serialized. Intra-block scheduling can't overlap because
//   the per-step barrier phase-locks all waves (VALU RAW-depends on own
//   MFMAs). m114: waves of DIFFERENT blocks co-schedule MFMA/VALU fully.
//   => BT=4, 512 blocks, 2 blocks/CU (r16 geometry otherwise unchanged).
//   Cost: chip MFMA doubles (144 MFMA/block-step is N-independent).
//   Hypothesis: blocks anti-phase -> step ~= max(matrix 1470, valu ~1200)
//   -> ~330-370us, sum>=115%. Falsified if sum stays ~98 (-> ~600us).
//   Junk-batch audit: phantom cols 8-15 stay encoded-zero (DPP fold
//   invariant); cols 4-7 = finite garbage produced/consumed by junk lanes
//   only; x-staging + out are bounds-guarded.
// Unchanged: i8 16x16x64 limb scheme, sigma byte-permute stores, integer
// DPP-fold, exp2-domain fused-denominator-free gates (r16's gate4s).

#define TT 512
#define HH 64
#define BT 4

typedef __attribute__((ext_vector_type(4))) int i32x4;

#define MFMAI8 __builtin_amdgcn_mfma_i32_16x16x64_i8

#define WSCALE 260096.0f   /* 32512 / 0.125 */
#define HSCALE 32512.0f    /* |h| <= 1      */
#define LOG2E  1.44269504f
constexpr float C_SIG = (float)(256.0 / (260096.0 * 32512.0) * 1.4426950408889634);
constexpr float C_TGH = (float)(2.0 * 256.0 / (260096.0 * 32512.0) * 1.4426950408889634);

__device__ __forceinline__ float exp2_hw(float x) {
    float r; asm("v_exp_f32 %0, %1" : "=v"(r) : "v"(x)); return r;
}
__device__ __forceinline__ float exp2n_hw(float x) {
    float r; asm("v_exp_f32 %0, -%1" : "=v"(r) : "v"(x)); return r;
}
// inputs pre-scaled: p0,p1,p3 by log2e; p2 by 2*log2e. c stays in real units.
__device__ __forceinline__ float gate4s(float p0, float p1, float p2, float p3, float& c) {
    float gi = __builtin_amdgcn_rcpf(1.f + exp2n_hw(p0));
    float gf = __builtin_amdgcn_rcpf(1.f + exp2n_hw(p1));
    float gg = 1.f - 2.f * __builtin_amdgcn_rcpf(1.f + exp2_hw(p2));
    float go = __builtin_amdgcn_rcpf(1.f + exp2n_hw(p3));
    c = fmaf(gf, c, gi * gg);
    float tc = 1.f - 2.f * __builtin_amdgcn_rcpf(1.f + exp2_hw(c * (2.f * LOG2E)));
    return go * tc;
}
// lane i <- lane (i^8) within each row of 16 (row_ror:8, HW-verified r6).
// All 64 lanes active at every call site (enclosing branches wave-uniform).
__device__ __forceinline__ int dpp_ror8_i(int v) {
    return __builtin_amdgcn_update_dpp(v, v, 0x128, 0xF, 0xF, true);
}
// 16 fp32 weights of one row-quarter -> i8 hi/lo limb frags, sigma-permuted:
// byte b of reg r holds W[base + 4*b + r].
__device__ __forceinline__ void cvtW16(const float* __restrict__ p, i32x4& hi, i32x4& lo) {
    #pragma unroll
    for (int r = 0; r < 4; ++r) {
        int hw = 0, lw = 0;
        #pragma unroll
        for (int b = 0; b < 4; ++b) {
            int wq = (int)rintf(p[4 * b + r] * WSCALE);   // |wq| <= 32512
            int h8 = (wq + 128) >> 8;                     // [-127,127]
            int l8 = wq - (h8 << 8);                      // [-128,127]
            hw |= (h8 & 0xFF) << (8 * b);
            lw |= (l8 & 0xFF) << (8 * b);
        }
        hi[r] = hw; lo[r] = lw;
    }
}

__global__ __launch_bounds__(512, 2) void lstm_mfma(
    const float* __restrict__ x,
    const float* __restrict__ Wih0, const float* __restrict__ Whh0,
    const float* __restrict__ bih0, const float* __restrict__ bhh0,
    const float* __restrict__ Wih1, const float* __restrict__ Whh1,
    const float* __restrict__ bih1, const float* __restrict__ bhh1,
    const float* __restrict__ fcW, const float* __restrict__ fcb,
    float* __restrict__ out)
{
    __shared__ float xs[8][TT + 1];                        // rows 4-7 unused
    // h limbs in i8 B-layout: [layer][buf][limb][row][byte];
    // byte jj of row holds unit u = (row>>4)*16 + sigma(jj). Lo-plane is
    // offset-binary (hq^0x80); encoded zero = 0x80. Rows n>=8 keep init
    // forever (phantom batches -> exact zero cols for the DPP fold).
    __shared__ __align__(16) signed char aH[2][2][2][64][16];  // 8 KB
    __shared__ float hF[8][HH + 1];
    __shared__ float fcw_s[HH];

    const int t    = threadIdx.x;     // 0..511
    const int lane = t & 63;
    const int v    = t >> 6;          // wave 0..7: owns tiles 2v, 2v+1
    const int b0   = blockIdx.x * BT;
    const int m    = lane & 15;       // A-row-within-tile AND D-col (=batch)
    const int q    = lane >> 4;       // quad
    const int ts   = m >> 3;          // tile-select within the pair
    const int bpk  = m & 7;           // this lane's batch (0-3 real, 4-7 junk)
    const int j    = 4 * (2 * v + ts) + q;   // this lane's hidden unit

    // ---- stage x (4 real rows); init limb planes (hi=0, lo=0x80) ----
    for (int i = t; i < BT * TT; i += 512)
        xs[i >> 9][i & (TT - 1)] = x[(size_t)(b0 + (i >> 9)) * TT + (i & (TT - 1))];
    {
        int* z = (int*)aH;
        for (int i = t; i < 2048; i += 512)
            z[i] = ((i >> 8) & 1) ? 0x80808080 : 0;   // 256 ints per limb plane
    }
    if (t < HH) fcw_s[t] = fcW[t];

    // ---- persistent A-frag weights (i8 limbs): tiles 2v,2v+1, 3 matrices ----
    // A-row m in tile ti -> gate-row rho = (m&3)*64 + 4*ti + (m>>2)
    i32x4 A0h[2], A0l[2], I1h[2], I1l[2], H1h[2], H1l[2];
    #pragma unroll
    for (int i = 0; i < 2; ++i) {
        const int rho = (m & 3) * 64 + 4 * (2 * v + i) + (m >> 2);
        cvtW16(Whh0 + rho * HH + q * 16, A0h[i], A0l[i]);
        cvtW16(Wih1 + rho * HH + q * 16, I1h[i], I1l[i]);
        cvtW16(Whh1 + rho * HH + q * 16, H1h[i], H1l[i]);
    }

    // ---- per-tile accumulator-init corrections: +128*rowsum(Whi) ----
    i32x4 corrA[2], corrB[2];
    {
        i32x4 ones; ones[0] = 0x01010101; ones[1] = 0x01010101;
        ones[2] = 0x01010101; ones[3] = 0x01010101;
        i32x4 zz = {0, 0, 0, 0};
        #pragma unroll
        for (int i = 0; i < 2; ++i) {
            i32x4 Sa = MFMAI8(A0h[i], ones, zz, 0, 0, 0);
            i32x4 Sb = MFMAI8(H1h[i], ones, MFMAI8(I1h[i], ones, zz, 0, 0, 0), 0, 0, 0);
            #pragma unroll
            for (int r = 0; r < 4; ++r) {
                corrA[i][r] = Sa[r] << 7;
                corrB[i][r] = Sb[r] << 7;
            }
        }
    }

    // ---- per-lane combine constants (pre-scaled into exp2 domain) ----
    float wxb[4], bia1[4], bia2[4];
    #pragma unroll
    for (int g = 0; g < 4; ++g) {
        const int r = g * 64 + j;
        const float sc = (g == 2) ? 2.f * LOG2E : LOG2E;
        wxb[g]  = Wih0[r] * sc;
        bia1[g] = (bih0[r] + bhh0[r]) * sc;
        bia2[g] = (bih1[r] + bhh1[r]) * sc;
    }
    // scatter target: row wl, byte wb = sigma(j&15)
    const int wl = ((j >> 4) << 4) + bpk;
    const int wb = ((j & 3) << 2) | ((j >> 2) & 3);
    float c1 = 0.f, c2 = 0.f;

    __syncthreads();

    // ---- peeled k=0: L1 only (h2(-1) stays encoded zero by init) ----
    {
        i32x4 bh1 = *(const i32x4*)&aH[0][0][0][lane][0];
        i32x4 bl1 = *(const i32x4*)&aH[0][0][1][lane][0];
        i32x4 aHH[2], aMD[2];
        #pragma unroll
        for (int i = 0; i < 2; ++i) {
            i32x4 z4 = {0, 0, 0, 0};
            aHH[i] = MFMAI8(A0h[i], bh1, z4, 0, 0, 0);
            aMD[i] = MFMAI8(A0l[i], bh1, MFMAI8(A0h[i], bl1, corrA[i], 0, 0, 0), 0, 0, 0);
        }
        float xb = xs[bpk][0];
        float pre[4];
        #pragma unroll
        for (int r = 0; r < 4; ++r) {
            int Pa = (aHH[0][r] << 8) + aMD[0][r];
            int Pb = (aHH[1][r] << 8) + aMD[1][r];
            int P  = Pa + dpp_ror8_i(Pb);
            const float Cr = (r == 2) ? C_TGH : C_SIG;
            pre[r] = fmaf((float)P, Cr, fmaf(wxb[r], xb, bia1[r]));
        }
        float h1v = gate4s(pre[0], pre[1], pre[2], pre[3], c1);
        int hq = __float_as_int(fmaf(h1v, HSCALE, 12582912.f)) - 0x4B400000;
        aH[0][1][0][wl][wb] = (signed char)(hq >> 8);
        aH[0][1][1][wl][wb] = (signed char)(hq ^ 0x80);
        __syncthreads();
    }

    // ---- main loop k=1..511: L1 computes h1(k); L2 computes h2(k-1) ----
    #pragma unroll 2
    for (int k = 1; k < TT; ++k) {
        const int p = k & 1, pn = p ^ 1;
        i32x4 bh1 = *(const i32x4*)&aH[0][p][0][lane][0];
        i32x4 bl1 = *(const i32x4*)&aH[0][p][1][lane][0];
        i32x4 bh2 = *(const i32x4*)&aH[1][p][0][lane][0];
        i32x4 bl2 = *(const i32x4*)&aH[1][p][1][lane][0];
        float xb = xs[bpk][k];

        // ---- issue ALL MFMAs first: L1 (completes first), then L2 ----
        i32x4 aHH[2], aMD[2], bHH[2], bMD[2];
        #pragma unroll
        for (int i = 0; i < 2; ++i) {
            i32x4 z4 = {0, 0, 0, 0};
            aHH[i] = MFMAI8(A0h[i], bh1, z4, 0, 0, 0);
            aMD[i] = MFMAI8(A0l[i], bh1, MFMAI8(A0h[i], bl1, corrA[i], 0, 0, 0), 0, 0, 0);
        }
        #pragma unroll
        for (int i = 0; i < 2; ++i) {
            i32x4 z4 = {0, 0, 0, 0};
            bHH[i] = MFMAI8(H1h[i], bh2, MFMAI8(I1h[i], bh1, z4, 0, 0, 0), 0, 0, 0);
            bMD[i] = MFMAI8(H1l[i], bh2,
                     MFMAI8(H1h[i], bl2,
                     MFMAI8(I1l[i], bh1,
                     MFMAI8(I1h[i], bl1, corrB[i], 0, 0, 0), 0, 0, 0), 0, 0, 0), 0, 0, 0);
        }
        __builtin_amdgcn_sched_barrier(0);   // pin: all MFMA issues precede folds

        // ---- L1 fold+gate+store ----
        {
            float pre[4];
            #pragma unroll
            for (int r = 0; r < 4; ++r) {
                int Pa = (aHH[0][r] << 8) + aMD[0][r];
                int Pb = (aHH[1][r] << 8) + aMD[1][r];
                int P  = Pa + dpp_ror8_i(Pb);
                const float Cr = (r == 2) ? C_TGH : C_SIG;
                pre[r] = fmaf((float)P, Cr, fmaf(wxb[r], xb, bia1[r]));
            }
            float h1v = gate4s(pre[0], pre[1], pre[2], pre[3], c1);
            int hq = __float_as_int(fmaf(h1v, HSCALE, 12582912.f)) - 0x4B400000;
            aH[0][pn][0][wl][wb] = (signed char)(hq >> 8);
            aH[0][pn][1][wl][wb] = (signed char)(hq ^ 0x80);
        }
        __builtin_amdgcn_sched_barrier(0);   // pin: L2 fold strictly after L1 work

        // ---- L2 fold+gate+store: h2(k-1) ----
        {
            float pre[4];
            #pragma unroll
            for (int r = 0; r < 4; ++r) {
                int Pc = (bHH[0][r] << 8) + bMD[0][r];
                int Pd = (bHH[1][r] << 8) + bMD[1][r];
                int P  = Pc + dpp_ror8_i(Pd);
                const float Cr = (r == 2) ? C_TGH : C_SIG;
                pre[r] = fmaf((float)P, Cr, bia2[r]);
            }
            float h2v = gate4s(pre[0], pre[1], pre[2], pre[3], c2);
            int hq = __float_as_int(fmaf(h2v, HSCALE, 12582912.f)) - 0x4B400000;
            aH[1][pn][0][wl][wb] = (signed char)(hq >> 8);
            aH[1][pn][1][wl][wb] = (signed char)(hq ^ 0x80);
        }
        __syncthreads();
    }

    // ---- epilogue: h2(TT-1) from h1(TT-1) and h2(TT-2) (both in buf 0) ----
    {
        i32x4 bh1 = *(const i32x4*)&aH[0][0][0][lane][0];
        i32x4 bl1 = *(const i32x4*)&aH[0][0][1][lane][0];
        i32x4 bh2 = *(const i32x4*)&aH[1][0][0][lane][0];
        i32x4 bl2 = *(const i32x4*)&aH[1][0][1][lane][0];
        i32x4 bHH[2], bMD[2];
        #pragma unroll
        for (int i = 0; i < 2; ++i) {
            i32x4 z4 = {0, 0, 0, 0};
            bHH[i] = MFMAI8(H1h[i], bh2, MFMAI8(I1h[i], bh1, z4, 0, 0, 0), 0, 0, 0);
            bMD[i] = MFMAI8(H1l[i], bh2,
                     MFMAI8(H1h[i], bl2,
                     MFMAI8(I1l[i], bh1,
                     MFMAI8(I1h[i], bl1, corrB[i], 0, 0, 0), 0, 0, 0), 0, 0, 0), 0, 0, 0);
        }
        float pre[4];
        #pragma unroll
        for (int r = 0; r < 4; ++r) {
            int Pc = (bHH[0][r] << 8) + bMD[0][r];
            int Pd = (bHH[1][r] << 8) + bMD[1][r];
            int P  = Pc + dpp_ror8_i(Pd);
            const float Cr = (r == 2) ? C_TGH : C_SIG;
            pre[r] = fmaf((float)P, Cr, bia2[r]);
        }
        float h2v = gate4s(pre[0], pre[1], pre[2], pre[3], c2);
        hF[bpk][j] = h2v;
    }
    __syncthreads();

    // ---- final FC: out[b] = fcW . h2(TT-1)[b] + fcb ----
    if (t < BT) {
        float s = fcb[0];
        #pragma unroll 8
        for (int jj = 0; jj < HH; ++jj)
            s = fmaf(hF[t][jj], fcw_s[jj], s);
        out[b0 + t] = s;
    }
}

extern "C" void kernel_launch(void* const* d_in, const int* in_sizes, int n_in,
                              void* d_out, int out_size, void* d_ws, size_t ws_size,
                              hipStream_t stream) {
    const float* x    = (const float*)d_in[0];
    const float* Wih0 = (const float*)d_in[1];
    const float* Whh0 = (const float*)d_in[2];
    const float* bih0 = (const float*)d_in[3];
    const float* bhh0 = (const float*)d_in[4];
    const float* Wih1 = (const float*)d_in[5];
    const float* Whh1 = (const float*)d_in[6];
    const float* bih1 = (const float*)d_in[7];
    const float* bhh1 = (const float*)d_in[8];
    const float* fcW  = (const float*)d_in[9];
    const float* fcb  = (const float*)d_in[10];
    float* out = (float*)d_out;

    lstm_mfma<<<dim3(2048 / BT), dim3(512), 0, stream>>>(
        x, Wih0, Whh0, bih0, bhh0, Wih1, Whh1, bih1, bhh1, fcW, fcb, out);
}

// Round 7
// 458.067 us; speedup vs baseline: 1.6539x; 1.6539x over previous
//
#include <hip/hip_runtime.h>

// LSTM: B=2048, T=512, I=1, H=64, L=2, O=1. fp32 in/out.
// Round 19: r16 base (best, 410us) + braid + proven trims.
//   r18 falsified cross-block overlap (2 blocks/CU never co-ran: 2x time).
//   Model: step 1926cy = matrix 734 + valu/trans ~700 + ~500 latency
//   bubbles that in-order issue can't fill. r16's SECOND sched_barrier
//   forbade the only filler: the independent L2 fold+gate chain.
//   Changes vs r16:
//   1) drop 2nd sched_barrier -> compiler braids L1/L2 fold+gate chains
//      into each other's exp/rcp latency shadows.
//   2) gate4f fused-denominator gates (r17-proven): 7 trans vs 10.
//   3) bMD 5-deep MFMA chain -> two 2-deep chains (corrB split per
//      matrix; junk-cols exactly 0 per chain; int adds associative =>
//      bit-exact; +1 add per reg-fold).
//   4) quantize: bytes taken directly from as_int(fma(h,32512,2^23+2^22)):
//      const 0x4B400000 has zero low-16 bits and hq in +-32512 can't carry
//      into bit 23, so byte0/byte1 of as_int == byte0/byte1 of hq. No sub.
// Unchanged: i8 16x16x64 limb scheme (W=(hi*256+lo)/260096, h/32512, lo
// offset-binary, corr folded into acc-init), sigma byte-permute stores,
// integer DPP-fold (all-lanes-active call sites), 1 barrier/step.

#define TT 512
#define HH 64
#define BT 8

typedef __attribute__((ext_vector_type(4))) int i32x4;

#define MFMAI8 __builtin_amdgcn_mfma_i32_16x16x64_i8

#define WSCALE 260096.0f   /* 32512 / 0.125 */
#define HSCALE 32512.0f    /* |h| <= 1      */
#define LOG2E  1.44269504f
constexpr float C_SIG = (float)(256.0 / (260096.0 * 32512.0) * 1.4426950408889634);
constexpr float C_TGH = (float)(2.0 * 256.0 / (260096.0 * 32512.0) * 1.4426950408889634);

__device__ __forceinline__ float exp2_hw(float x) {
    float r; asm("v_exp_f32 %0, %1" : "=v"(r) : "v"(x)); return r;
}
__device__ __forceinline__ float exp2n_hw(float x) {
    float r; asm("v_exp_f32 %0, -%1" : "=v"(r) : "v"(x)); return r;
}
// Fused-denominator LSTM gates (r17-proven). Inputs pre-scaled: p0,p1,p3 by
// log2e, p2 by 2*log2e. c in real units. 5 exp + 2 rcp.
__device__ __forceinline__ float gate4f(float p0, float p1, float p2, float p3, float& c) {
    float ia = exp2n_hw(p0);            // e^{-i}
    float fb = exp2n_hw(p1);            // e^{-f}
    float gb = exp2_hw(p2);             // e^{2g}
    float ob = exp2n_hw(p3);            // e^{-o}
    float A = 1.f + ia, B = 1.f + gb, F = 1.f + fb;
    float t1  = A * B;
    float den = t1 * F;
    float num = fmaf(c, t1, (B - 2.f) * F);
    c = num * __builtin_amdgcn_rcpf(den);
    float e2 = exp2_hw(fminf(c * (2.f * LOG2E), 126.f));   // guard inf*0
    float C  = 1.f + e2;
    float r2 = __builtin_amdgcn_rcpf((1.f + ob) * C);
    return (C - 2.f) * r2;
}
// lane i <- lane (i^8) within each row of 16 (row_ror:8, HW-verified r6).
// All 64 lanes active at every call site (enclosing branches wave-uniform).
__device__ __forceinline__ int dpp_ror8_i(int v) {
    return __builtin_amdgcn_update_dpp(v, v, 0x128, 0xF, 0xF, true);
}
// 16 fp32 weights of one row-quarter -> i8 hi/lo limb frags, sigma-permuted:
// byte b of reg r holds W[base + 4*b + r].
__device__ __forceinline__ void cvtW16(const float* __restrict__ p, i32x4& hi, i32x4& lo) {
    #pragma unroll
    for (int r = 0; r < 4; ++r) {
        int hw = 0, lw = 0;
        #pragma unroll
        for (int b = 0; b < 4; ++b) {
            int wq = (int)rintf(p[4 * b + r] * WSCALE);   // |wq| <= 32512
            int h8 = (wq + 128) >> 8;                     // [-127,127]
            int l8 = wq - (h8 << 8);                      // [-128,127]
            hw |= (h8 & 0xFF) << (8 * b);
            lw |= (l8 & 0xFF) << (8 * b);
        }
        hi[r] = hw; lo[r] = lw;
    }
}

__global__ __launch_bounds__(512) void lstm_mfma(
    const float* __restrict__ x,
    const float* __restrict__ Wih0, const float* __restrict__ Whh0,
    const float* __restrict__ bih0, const float* __restrict__ bhh0,
    const float* __restrict__ Wih1, const float* __restrict__ Whh1,
    const float* __restrict__ bih1, const float* __restrict__ bhh1,
    const float* __restrict__ fcW, const float* __restrict__ fcb,
    float* __restrict__ out)
{
    __shared__ float xs[BT][TT + 1];                        // 16.4 KB
    // h limbs in i8 B-layout: [layer][buf][limb][row][byte];
    // byte jj of row holds unit u = (row>>4)*16 + sigma(jj). Lo-plane is
    // offset-binary (hq^0x80); encoded zero = 0x80. Rows n>=8 keep init
    // forever (phantom cols -> exact zeros for the DPP fold).
    __shared__ __align__(16) signed char aH[2][2][2][64][16];  // 8 KB
    __shared__ float hF[BT][HH + 1];
    __shared__ float fcw_s[HH];

    const int t    = threadIdx.x;     // 0..511
    const int lane = t & 63;
    const int v    = t >> 6;          // wave 0..7: owns tiles 2v, 2v+1
    const int b0   = blockIdx.x * BT;
    const int m    = lane & 15;       // A-row-within-tile AND D-col (=batch)
    const int q    = lane >> 4;       // quad
    const int ts   = m >> 3;          // tile-select within the pair
    const int bpk  = m & 7;           // this lane's batch
    const int j    = 4 * (2 * v + ts) + q;   // this lane's hidden unit

    // ---- stage x; init limb planes (hi=0, lo=0x80 = encoded zero) ----
    for (int i = t; i < BT * TT; i += 512)
        xs[i >> 9][i & (TT - 1)] = x[(size_t)(b0 + (i >> 9)) * TT + (i & (TT - 1))];
    {
        int* z = (int*)aH;
        for (int i = t; i < 2048; i += 512)
            z[i] = ((i >> 8) & 1) ? 0x80808080 : 0;   // 256 ints per limb plane
    }
    if (t < HH) fcw_s[t] = fcW[t];

    // ---- persistent A-frag weights (i8 limbs): tiles 2v,2v+1, 3 matrices ----
    // A-row m in tile ti -> gate-row rho = (m&3)*64 + 4*ti + (m>>2)
    i32x4 A0h[2], A0l[2], I1h[2], I1l[2], H1h[2], H1l[2];
    #pragma unroll
    for (int i = 0; i < 2; ++i) {
        const int rho = (m & 3) * 64 + 4 * (2 * v + i) + (m >> 2);
        cvtW16(Whh0 + rho * HH + q * 16, A0h[i], A0l[i]);
        cvtW16(Wih1 + rho * HH + q * 16, I1h[i], I1l[i]);
        cvtW16(Whh1 + rho * HH + q * 16, H1h[i], H1l[i]);
    }

    // ---- per-tile/per-matrix accumulator-init corrections ----
    // corrA: +128*rowsum(A0h); corrBI: +128*rowsum(I1h); corrBH: +128*rowsum(H1h)
    i32x4 corrA[2], corrBI[2], corrBH[2];
    {
        i32x4 ones; ones[0] = 0x01010101; ones[1] = 0x01010101;
        ones[2] = 0x01010101; ones[3] = 0x01010101;
        i32x4 zz = {0, 0, 0, 0};
        #pragma unroll
        for (int i = 0; i < 2; ++i) {
            i32x4 Sa = MFMAI8(A0h[i], ones, zz, 0, 0, 0);
            i32x4 Si = MFMAI8(I1h[i], ones, zz, 0, 0, 0);
            i32x4 Sh = MFMAI8(H1h[i], ones, zz, 0, 0, 0);
            #pragma unroll
            for (int r = 0; r < 4; ++r) {
                corrA[i][r]  = Sa[r] << 7;
                corrBI[i][r] = Si[r] << 7;
                corrBH[i][r] = Sh[r] << 7;
            }
        }
    }

    // ---- per-lane combine constants (pre-scaled into exp2 domain) ----
    float wxb[4], bia1[4], bia2[4];
    #pragma unroll
    for (int g = 0; g < 4; ++g) {
        const int r = g * 64 + j;
        const float sc = (g == 2) ? 2.f * LOG2E : LOG2E;
        wxb[g]  = Wih0[r] * sc;
        bia1[g] = (bih0[r] + bhh0[r]) * sc;
        bia2[g] = (bih1[r] + bhh1[r]) * sc;
    }
    // scatter target: row wl, byte wb = sigma(j&15)
    const int wl = ((j >> 4) << 4) + bpk;
    const int wb = ((j & 3) << 2) | ((j >> 2) & 3);
    float c1 = 0.f, c2 = 0.f;

    __syncthreads();

    // ---- peeled k=0: L1 only (h2(-1) stays encoded zero by init) ----
    {
        i32x4 bh1 = *(const i32x4*)&aH[0][0][0][lane][0];
        i32x4 bl1 = *(const i32x4*)&aH[0][0][1][lane][0];
        i32x4 aHH[2], aMD[2];
        #pragma unroll
        for (int i = 0; i < 2; ++i) {
            i32x4 z4 = {0, 0, 0, 0};
            aHH[i] = MFMAI8(A0h[i], bh1, z4, 0, 0, 0);
            aMD[i] = MFMAI8(A0l[i], bh1, MFMAI8(A0h[i], bl1, corrA[i], 0, 0, 0), 0, 0, 0);
        }
        float xb = xs[bpk][0];
        float pre[4];
        #pragma unroll
        for (int r = 0; r < 4; ++r) {
            int Pa = (aHH[0][r] << 8) + aMD[0][r];
            int Pb = (aHH[1][r] << 8) + aMD[1][r];
            int P  = Pa + dpp_ror8_i(Pb);
            const float Cr = (r == 2) ? C_TGH : C_SIG;
            pre[r] = fmaf((float)P, Cr, fmaf(wxb[r], xb, bia1[r]));
        }
        float h1v = gate4f(pre[0], pre[1], pre[2], pre[3], c1);
        int u = __float_as_int(fmaf(h1v, HSCALE, 12582912.f));
        aH[0][1][0][wl][wb] = (signed char)(u >> 8);
        aH[0][1][1][wl][wb] = (signed char)(u ^ 0x80);
        __syncthreads();
    }

    // ---- main loop k=1..511: L1 computes h1(k); L2 computes h2(k-1) ----
    #pragma unroll 2
    for (int k = 1; k < TT; ++k) {
        const int p = k & 1, pn = p ^ 1;
        i32x4 bh1 = *(const i32x4*)&aH[0][p][0][lane][0];
        i32x4 bl1 = *(const i32x4*)&aH[0][p][1][lane][0];
        i32x4 bh2 = *(const i32x4*)&aH[1][p][0][lane][0];
        i32x4 bl2 = *(const i32x4*)&aH[1][p][1][lane][0];
        float xb = xs[bpk][k];

        // ---- issue ALL MFMAs first: L1 (completes first), then L2 ----
        i32x4 aHH[2], aMD[2], bHH[2], bMD1[2], bMD2[2];
        #pragma unroll
        for (int i = 0; i < 2; ++i) {
            i32x4 z4 = {0, 0, 0, 0};
            aHH[i] = MFMAI8(A0h[i], bh1, z4, 0, 0, 0);
            aMD[i] = MFMAI8(A0l[i], bh1, MFMAI8(A0h[i], bl1, corrA[i], 0, 0, 0), 0, 0, 0);
        }
        #pragma unroll
        for (int i = 0; i < 2; ++i) {
            i32x4 z4 = {0, 0, 0, 0};
            bHH[i]  = MFMAI8(H1h[i], bh2, MFMAI8(I1h[i], bh1, z4, 0, 0, 0), 0, 0, 0);
            // two independent 2-deep mid-limb chains (bit-exact refactor)
            bMD1[i] = MFMAI8(I1l[i], bh1, MFMAI8(I1h[i], bl1, corrBI[i], 0, 0, 0), 0, 0, 0);
            bMD2[i] = MFMAI8(H1l[i], bh2, MFMAI8(H1h[i], bl2, corrBH[i], 0, 0, 0), 0, 0, 0);
        }
        __builtin_amdgcn_sched_barrier(0);   // pin: all MFMA issues precede folds

        // ---- L1 and L2 fold+gate+store: NO sched_barrier between them ----
        // (independent chains; compiler braids them into each other's
        //  exp/rcp latency shadows)
        {
            float pre[4];
            #pragma unroll
            for (int r = 0; r < 4; ++r) {
                int Pa = (aHH[0][r] << 8) + aMD[0][r];
                int Pb = (aHH[1][r] << 8) + aMD[1][r];
                int P  = Pa + dpp_ror8_i(Pb);
                const float Cr = (r == 2) ? C_TGH : C_SIG;
                pre[r] = fmaf((float)P, Cr, fmaf(wxb[r], xb, bia1[r]));
            }
            float h1v = gate4f(pre[0], pre[1], pre[2], pre[3], c1);
            int u = __float_as_int(fmaf(h1v, HSCALE, 12582912.f));
            aH[0][pn][0][wl][wb] = (signed char)(u >> 8);
            aH[0][pn][1][wl][wb] = (signed char)(u ^ 0x80);
        }
        {
            float pre[4];
            #pragma unroll
            for (int r = 0; r < 4; ++r) {
                int Pc = (bHH[0][r] << 8) + bMD1[0][r] + bMD2[0][r];
                int Pd = (bHH[1][r] << 8) + bMD1[1][r] + bMD2[1][r];
                int P  = Pc + dpp_ror8_i(Pd);
                const float Cr = (r == 2) ? C_TGH : C_SIG;
                pre[r] = fmaf((float)P, Cr, bia2[r]);
            }
            float h2v = gate4f(pre[0], pre[1], pre[2], pre[3], c2);
            int u = __float_as_int(fmaf(h2v, HSCALE, 12582912.f));
            aH[1][pn][0][wl][wb] = (signed char)(u >> 8);
            aH[1][pn][1][wl][wb] = (signed char)(u ^ 0x80);
        }
        __syncthreads();
    }

    // ---- epilogue: h2(TT-1) from h1(TT-1) and h2(TT-2) (both in buf 0) ----
    {
        i32x4 bh1 = *(const i32x4*)&aH[0][0][0][lane][0];
        i32x4 bl1 = *(const i32x4*)&aH[0][0][1][lane][0];
        i32x4 bh2 = *(const i32x4*)&aH[1][0][0][lane][0];
        i32x4 bl2 = *(const i32x4*)&aH[1][0][1][lane][0];
        i32x4 bHH[2], bMD1[2], bMD2[2];
        #pragma unroll
        for (int i = 0; i < 2; ++i) {
            i32x4 z4 = {0, 0, 0, 0};
            bHH[i]  = MFMAI8(H1h[i], bh2, MFMAI8(I1h[i], bh1, z4, 0, 0, 0), 0, 0, 0);
            bMD1[i] = MFMAI8(I1l[i], bh1, MFMAI8(I1h[i], bl1, corrBI[i], 0, 0, 0), 0, 0, 0);
            bMD2[i] = MFMAI8(H1l[i], bh2, MFMAI8(H1h[i], bl2, corrBH[i], 0, 0, 0), 0, 0, 0);
        }
        float pre[4];
        #pragma unroll
        for (int r = 0; r < 4; ++r) {
            int Pc = (bHH[0][r] << 8) + bMD1[0][r] + bMD2[0][r];
            int Pd = (bHH[1][r] << 8) + bMD1[1][r] + bMD2[1][r];
            int P  = Pc + dpp_ror8_i(Pd);
            const float Cr = (r == 2) ? C_TGH : C_SIG;
            pre[r] = fmaf((float)P, Cr, bia2[r]);
        }
        float h2v = gate4f(pre[0], pre[1], pre[2], pre[3], c2);
        hF[bpk][j] = h2v;
    }
    __syncthreads();

    // ---- final FC: out[b] = fcW . h2(TT-1)[b] + fcb ----
    if (t < BT) {
        float s = fcb[0];
        #pragma unroll 8
        for (int jj = 0; jj < HH; ++jj)
            s = fmaf(hF[t][jj], fcw_s[jj], s);
        out[b0 + t] = s;
    }
}

extern "C" void kernel_launch(void* const* d_in, const int* in_sizes, int n_in,
                              void* d_out, int out_size, void* d_ws, size_t ws_size,
                              hipStream_t stream) {
    const float* x    = (const float*)d_in[0];
    const float* Wih0 = (const float*)d_in[1];
    const float* Whh0 = (const float*)d_in[2];
    const float* bih0 = (const float*)d_in[3];
    const float* bhh0 = (const float*)d_in[4];
    const float* Wih1 = (const float*)d_in[5];
    const float* Whh1 = (const float*)d_in[6];
    const float* bih1 = (const float*)d_in[7];
    const float* bhh1 = (const float*)d_in[8];
    const float* fcW  = (const float*)d_in[9];
    const float* fcb  = (const float*)d_in[10];
    float* out = (float*)d_out;

    lstm_mfma<<<dim3(2048 / BT), dim3(512), 0, stream>>>(
        x, Wih0, Whh0, bih0, bhh0, Wih1, Whh1, bih1, bhh1, fcW, fcb, out);
}

// Round 8
// 428.261 us; speedup vs baseline: 1.7690x; 1.0696x over previous
//
#include <hip/hip_runtime.h>

// LSTM: B=2048, T=512, I=1, H=64, L=2, O=1. fp32 in/out.
// Round 20: r16 EXACT schedule + three safe trims.
//   r19 post-mortem: dropping the 2nd sched_barrier let the compiler braid
//   folds badly (sum 98%->82%, 410->470us); also lost launch_bounds(512,2).
//   The r16 issue order (MFMA burst -> fence -> L1 fold -> fence -> L2 fold)
//   is the best found. Restored byte-for-byte. Trims on top:
//   1) corr folded into FLOAT bias (pre = fma(P_raw, Cr, bia + corr*Cr)):
//      all 6 MFMA chains start from one persistent zero quad -> no per-step
//      v_mov copies of corr quads, -16 live VGPRs. Error <= 2.8e-6 on
//      pre-acts (cvt rounding of P_raw vs P_raw+corr), invisible vs the
//      1.5e-5 h-quant floor. corr per-lane = ts-select of setup ones-MFMA
//      rowsums (col-independent => select == dpp-fold).
//   2) gate4f fused-denominator gates (r17-proven): 7 trans vs 10.
//   3) copyless quantize (r19-verified exact): bytes straight from
//      as_int(fma(h,32512,2^23+2^22)).
// Unchanged: i8 16x16x64 limb scheme, sigma byte-permute stores, integer
// DPP-fold (all-lanes-active), 1 barrier/step, launch_bounds(512,2).

#define TT 512
#define HH 64
#define BT 8

typedef __attribute__((ext_vector_type(4))) int i32x4;

#define MFMAI8 __builtin_amdgcn_mfma_i32_16x16x64_i8

#define WSCALE 260096.0f   /* 32512 / 0.125 */
#define HSCALE 32512.0f    /* |h| <= 1      */
#define LOG2E  1.44269504f
constexpr float C_SIG = (float)(256.0 / (260096.0 * 32512.0) * 1.4426950408889634);
constexpr float C_TGH = (float)(2.0 * 256.0 / (260096.0 * 32512.0) * 1.4426950408889634);

__device__ __forceinline__ float exp2_hw(float x) {
    float r; asm("v_exp_f32 %0, %1" : "=v"(r) : "v"(x)); return r;
}
__device__ __forceinline__ float exp2n_hw(float x) {
    float r; asm("v_exp_f32 %0, -%1" : "=v"(r) : "v"(x)); return r;
}
// Fused-denominator LSTM gates (r17-proven). Inputs pre-scaled: p0,p1,p3 by
// log2e, p2 by 2*log2e. c in real units. 5 exp + 2 rcp.
__device__ __forceinline__ float gate4f(float p0, float p1, float p2, float p3, float& c) {
    float ia = exp2n_hw(p0);            // e^{-i}
    float fb = exp2n_hw(p1);            // e^{-f}
    float gb = exp2_hw(p2);             // e^{2g}
    float ob = exp2n_hw(p3);            // e^{-o}
    float A = 1.f + ia, B = 1.f + gb, F = 1.f + fb;
    float t1  = A * B;
    float den = t1 * F;
    float num = fmaf(c, t1, (B - 2.f) * F);
    c = num * __builtin_amdgcn_rcpf(den);
    float e2 = exp2_hw(fminf(c * (2.f * LOG2E), 126.f));   // guard inf*0
    float C  = 1.f + e2;
    float r2 = __builtin_amdgcn_rcpf((1.f + ob) * C);
    return (C - 2.f) * r2;
}
// lane i <- lane (i^8) within each row of 16 (row_ror:8, HW-verified r6).
// All 64 lanes active at every call site (enclosing branches wave-uniform).
__device__ __forceinline__ int dpp_ror8_i(int v) {
    return __builtin_amdgcn_update_dpp(v, v, 0x128, 0xF, 0xF, true);
}
// 16 fp32 weights of one row-quarter -> i8 hi/lo limb frags, sigma-permuted:
// byte b of reg r holds W[base + 4*b + r].
__device__ __forceinline__ void cvtW16(const float* __restrict__ p, i32x4& hi, i32x4& lo) {
    #pragma unroll
    for (int r = 0; r < 4; ++r) {
        int hw = 0, lw = 0;
        #pragma unroll
        for (int b = 0; b < 4; ++b) {
            int wq = (int)rintf(p[4 * b + r] * WSCALE);   // |wq| <= 32512
            int h8 = (wq + 128) >> 8;                     // [-127,127]
            int l8 = wq - (h8 << 8);                      // [-128,127]
            hw |= (h8 & 0xFF) << (8 * b);
            lw |= (l8 & 0xFF) << (8 * b);
        }
        hi[r] = hw; lo[r] = lw;
    }
}

__global__ __launch_bounds__(512, 2) void lstm_mfma(
    const float* __restrict__ x,
    const float* __restrict__ Wih0, const float* __restrict__ Whh0,
    const float* __restrict__ bih0, const float* __restrict__ bhh0,
    const float* __restrict__ Wih1, const float* __restrict__ Whh1,
    const float* __restrict__ bih1, const float* __restrict__ bhh1,
    const float* __restrict__ fcW, const float* __restrict__ fcb,
    float* __restrict__ out)
{
    __shared__ float xs[BT][TT + 1];                        // 16.4 KB
    // h limbs in i8 B-layout: [layer][buf][limb][row][byte];
    // byte jj of row holds unit u = (row>>4)*16 + sigma(jj). Lo-plane is
    // offset-binary (hq^0x80); encoded zero = 0x80. Rows n>=8 keep init
    // forever (phantom cols -> exact zeros for the DPP fold).
    __shared__ __align__(16) signed char aH[2][2][2][64][16];  // 8 KB
    __shared__ float hF[BT][HH + 1];
    __shared__ float fcw_s[HH];

    const int t    = threadIdx.x;     // 0..511
    const int lane = t & 63;
    const int v    = t >> 6;          // wave 0..7: owns tiles 2v, 2v+1
    const int b0   = blockIdx.x * BT;
    const int m    = lane & 15;       // A-row-within-tile AND D-col (=batch)
    const int q    = lane >> 4;       // quad
    const int ts   = m >> 3;          // tile-select within the pair
    const int bpk  = m & 7;           // this lane's batch
    const int j    = 4 * (2 * v + ts) + q;   // this lane's hidden unit

    // ---- stage x; init limb planes (hi=0, lo=0x80 = encoded zero) ----
    for (int i = t; i < BT * TT; i += 512)
        xs[i >> 9][i & (TT - 1)] = x[(size_t)(b0 + (i >> 9)) * TT + (i & (TT - 1))];
    {
        int* z = (int*)aH;
        for (int i = t; i < 2048; i += 512)
            z[i] = ((i >> 8) & 1) ? 0x80808080 : 0;   // 256 ints per limb plane
    }
    if (t < HH) fcw_s[t] = fcW[t];

    // ---- persistent A-frag weights (i8 limbs): tiles 2v,2v+1, 3 matrices ----
    // A-row m in tile ti -> gate-row rho = (m&3)*64 + 4*ti + (m>>2)
    i32x4 A0h[2], A0l[2], I1h[2], I1l[2], H1h[2], H1l[2];
    #pragma unroll
    for (int i = 0; i < 2; ++i) {
        const int rho = (m & 3) * 64 + 4 * (2 * v + i) + (m >> 2);
        cvtW16(Whh0 + rho * HH + q * 16, A0h[i], A0l[i]);
        cvtW16(Wih1 + rho * HH + q * 16, I1h[i], I1l[i]);
        cvtW16(Whh1 + rho * HH + q * 16, H1h[i], H1l[i]);
    }

    // ---- per-lane combine constants (pre-scaled into exp2 domain) ----
    float wxb[4], bia1[4], bia2[4];
    #pragma unroll
    for (int g = 0; g < 4; ++g) {
        const int r = g * 64 + j;
        const float sc = (g == 2) ? 2.f * LOG2E : LOG2E;
        wxb[g]  = Wih0[r] * sc;
        bia1[g] = (bih0[r] + bhh0[r]) * sc;
        bia2[g] = (bih1[r] + bhh1[r]) * sc;
    }

    // ---- fold offset-binary corrections into the float biases ----
    // ones-MFMA rowsums: S[r] at lane(m,q) = rowsum(A-tile row 4q+r), col-
    // independent => ts-select == dpp-fold. corr = 128*rowsum; bia += corr*Cr.
    {
        i32x4 ones; ones[0] = 0x01010101; ones[1] = 0x01010101;
        ones[2] = 0x01010101; ones[3] = 0x01010101;
        i32x4 zz = {0, 0, 0, 0};
        i32x4 Sa0 = MFMAI8(A0h[0], ones, zz, 0, 0, 0);
        i32x4 Sa1 = MFMAI8(A0h[1], ones, zz, 0, 0, 0);
        i32x4 Sb0 = MFMAI8(H1h[0], ones, MFMAI8(I1h[0], ones, zz, 0, 0, 0), 0, 0, 0);
        i32x4 Sb1 = MFMAI8(H1h[1], ones, MFMAI8(I1h[1], ones, zz, 0, 0, 0), 0, 0, 0);
        #pragma unroll
        for (int g = 0; g < 4; ++g) {
            const float Cg = (g == 2) ? C_TGH : C_SIG;
            float cA = (float)((ts ? Sa1[g] : Sa0[g]) << 7);
            float cB = (float)((ts ? Sb1[g] : Sb0[g]) << 7);
            bia1[g] = fmaf(cA, Cg, bia1[g]);
            bia2[g] = fmaf(cB, Cg, bia2[g]);
        }
    }

    // scatter target: row wl, byte wb = sigma(j&15)
    const int wl = ((j >> 4) << 4) + bpk;
    const int wb = ((j & 3) << 2) | ((j >> 2) & 3);
    float c1 = 0.f, c2 = 0.f;
    const i32x4 z4 = {0, 0, 0, 0};    // persistent zero quad (C operand)

    __syncthreads();

    // ---- peeled k=0: L1 only (h2(-1) stays encoded zero by init) ----
    {
        i32x4 bh1 = *(const i32x4*)&aH[0][0][0][lane][0];
        i32x4 bl1 = *(const i32x4*)&aH[0][0][1][lane][0];
        i32x4 aHH[2], aMD[2];
        #pragma unroll
        for (int i = 0; i < 2; ++i) {
            aHH[i] = MFMAI8(A0h[i], bh1, z4, 0, 0, 0);
            aMD[i] = MFMAI8(A0l[i], bh1, MFMAI8(A0h[i], bl1, z4, 0, 0, 0), 0, 0, 0);
        }
        float xb = xs[bpk][0];
        float pre[4];
        #pragma unroll
        for (int r = 0; r < 4; ++r) {
            int Pa = (aHH[0][r] << 8) + aMD[0][r];
            int Pb = (aHH[1][r] << 8) + aMD[1][r];
            int P  = Pa + dpp_ror8_i(Pb);
            const float Cr = (r == 2) ? C_TGH : C_SIG;
            pre[r] = fmaf((float)P, Cr, fmaf(wxb[r], xb, bia1[r]));
        }
        float h1v = gate4f(pre[0], pre[1], pre[2], pre[3], c1);
        int u = __float_as_int(fmaf(h1v, HSCALE, 12582912.f));
        aH[0][1][0][wl][wb] = (signed char)(u >> 8);
        aH[0][1][1][wl][wb] = (signed char)(u ^ 0x80);
        __syncthreads();
    }

    // ---- main loop k=1..511: L1 computes h1(k); L2 computes h2(k-1) ----
    #pragma unroll 2
    for (int k = 1; k < TT; ++k) {
        const int p = k & 1, pn = p ^ 1;
        i32x4 bh1 = *(const i32x4*)&aH[0][p][0][lane][0];
        i32x4 bl1 = *(const i32x4*)&aH[0][p][1][lane][0];
        i32x4 bh2 = *(const i32x4*)&aH[1][p][0][lane][0];
        i32x4 bl2 = *(const i32x4*)&aH[1][p][1][lane][0];
        float xb = xs[bpk][k];

        // ---- issue ALL MFMAs first: L1 (completes first), then L2 ----
        i32x4 aHH[2], aMD[2], bHH[2], bMD[2];
        #pragma unroll
        for (int i = 0; i < 2; ++i) {
            aHH[i] = MFMAI8(A0h[i], bh1, z4, 0, 0, 0);
            aMD[i] = MFMAI8(A0l[i], bh1, MFMAI8(A0h[i], bl1, z4, 0, 0, 0), 0, 0, 0);
        }
        #pragma unroll
        for (int i = 0; i < 2; ++i) {
            bHH[i] = MFMAI8(H1h[i], bh2, MFMAI8(I1h[i], bh1, z4, 0, 0, 0), 0, 0, 0);
            bMD[i] = MFMAI8(H1l[i], bh2,
                     MFMAI8(H1h[i], bl2,
                     MFMAI8(I1l[i], bh1,
                     MFMAI8(I1h[i], bl1, z4, 0, 0, 0), 0, 0, 0), 0, 0, 0), 0, 0, 0);
        }
        __builtin_amdgcn_sched_barrier(0);   // pin: all MFMA issues precede folds

        // ---- L1 fold+gate+store: overlaps L2's MFMA execution ----
        {
            float pre[4];
            #pragma unroll
            for (int r = 0; r < 4; ++r) {
                int Pa = (aHH[0][r] << 8) + aMD[0][r];
                int Pb = (aHH[1][r] << 8) + aMD[1][r];
                int P  = Pa + dpp_ror8_i(Pb);
                const float Cr = (r == 2) ? C_TGH : C_SIG;
                pre[r] = fmaf((float)P, Cr, fmaf(wxb[r], xb, bia1[r]));
            }
            float h1v = gate4f(pre[0], pre[1], pre[2], pre[3], c1);
            int u = __float_as_int(fmaf(h1v, HSCALE, 12582912.f));
            aH[0][pn][0][wl][wb] = (signed char)(u >> 8);
            aH[0][pn][1][wl][wb] = (signed char)(u ^ 0x80);
        }
        __builtin_amdgcn_sched_barrier(0);   // pin: L2 fold strictly after L1 work

        // ---- L2 fold+gate+store: h2(k-1) ----
        {
            float pre[4];
            #pragma unroll
            for (int r = 0; r < 4; ++r) {
                int Pc = (bHH[0][r] << 8) + bMD[0][r];
                int Pd = (bHH[1][r] << 8) + bMD[1][r];
                int P  = Pc + dpp_ror8_i(Pd);
                const float Cr = (r == 2) ? C_TGH : C_SIG;
                pre[r] = fmaf((float)P, Cr, bia2[r]);
            }
            float h2v = gate4f(pre[0], pre[1], pre[2], pre[3], c2);
            int u = __float_as_int(fmaf(h2v, HSCALE, 12582912.f));
            aH[1][pn][0][wl][wb] = (signed char)(u >> 8);
            aH[1][pn][1][wl][wb] = (signed char)(u ^ 0x80);
        }
        __syncthreads();
    }

    // ---- epilogue: h2(TT-1) from h1(TT-1) and h2(TT-2) (both in buf 0) ----
    {
        i32x4 bh1 = *(const i32x4*)&aH[0][0][0][lane][0];
        i32x4 bl1 = *(const i32x4*)&aH[0][0][1][lane][0];
        i32x4 bh2 = *(const i32x4*)&aH[1][0][0][lane][0];
        i32x4 bl2 = *(const i32x4*)&aH[1][0][1][lane][0];
        i32x4 bHH[2], bMD[2];
        #pragma unroll
        for (int i = 0; i < 2; ++i) {
            bHH[i] = MFMAI8(H1h[i], bh2, MFMAI8(I1h[i], bh1, z4, 0, 0, 0), 0, 0, 0);
            bMD[i] = MFMAI8(H1l[i], bh2,
                     MFMAI8(H1h[i], bl2,
                     MFMAI8(I1l[i], bh1,
                     MFMAI8(I1h[i], bl1, z4, 0, 0, 0), 0, 0, 0), 0, 0, 0), 0, 0, 0);
        }
        float pre[4];
        #pragma unroll
        for (int r = 0; r < 4; ++r) {
            int Pc = (bHH[0][r] << 8) + bMD[0][r];
            int Pd = (bHH[1][r] << 8) + bMD[1][r];
            int P  = Pc + dpp_ror8_i(Pd);
            const float Cr = (r == 2) ? C_TGH : C_SIG;
            pre[r] = fmaf((float)P, Cr, bia2[r]);
        }
        float h2v = gate4f(pre[0], pre[1], pre[2], pre[3], c2);
        hF[bpk][j] = h2v;
    }
    __syncthreads();

    // ---- final FC: out[b] = fcW . h2(TT-1)[b] + fcb ----
    if (t < BT) {
        float s = fcb[0];
        #pragma unroll 8
        for (int jj = 0; jj < HH; ++jj)
            s = fmaf(hF[t][jj], fcw_s[jj], s);
        out[b0 + t] = s;
    }
}

extern "C" void kernel_launch(void* const* d_in, const int* in_sizes, int n_in,
                              void* d_out, int out_size, void* d_ws, size_t ws_size,
                              hipStream_t stream) {
    const float* x    = (const float*)d_in[0];
    const float* Wih0 = (const float*)d_in[1];
    const float* Whh0 = (const float*)d_in[2];
    const float* bih0 = (const float*)d_in[3];
    const float* bhh0 = (const float*)d_in[4];
    const float* Wih1 = (const float*)d_in[5];
    const float* Whh1 = (const float*)d_in[6];
    const float* bih1 = (const float*)d_in[7];
    const float* bhh1 = (const float*)d_in[8];
    const float* fcW  = (const float*)d_in[9];
    const float* fcb  = (const float*)d_in[10];
    float* out = (float*)d_out;

    lstm_mfma<<<dim3(2048 / BT), dim3(512), 0, stream>>>(
        x, Wih0, Whh0, bih0, bhh0, Wih1, Whh1, bih1, bhh1, fcW, fcb, out);
}

// Round 9
// 420.442 us; speedup vs baseline: 1.8019x; 1.0186x over previous
//
#include <hip/hip_runtime.h>

// LSTM: B=2048, T=512, I=1, H=64, L=2, O=1. fp32 in/out.
// Round 21: REVERT to r16 exactly - the best harness-verified variant
// (418.08us headline, absmax 6.1e-5).
//   Session converged: r14/r16/r17/r18/r19/r20 all land 410-428us with
//   MfmaUtil+VALUBusy = 93-98% across five distinct geometries => MFMA and
//   VALU issue are ADDITIVE per SIMD on gfx950 (role-split, setprio,
//   2-blocks/CU, braiding all failed to overlap). Floor per SIMD-step:
//   matrix 620cy (3-limb i8, precision-mandated: r20 measured 100x
//   pre-act->output error amplification, killing 2-limb) + trans 450cy
//   (7/gate4, minimal) + regular VALU ~700cy + ~135cy post-barrier LDS
//   bubble (structural all-to-all h-exchange). We are at ~93% of it.
//   r20's trims (corr->float-bias, gate4f, copyless quant) measured
//   collectively -2.4% and 4x worse absmax => reverted.
// Structure (r16): 512 thr / 8 waves; each wave owns tile-pair {2v,2v+1}
// for BOTH layers; per step: [4 ds_read] -> [issue 6 L1-MFMA + 12 L2-MFMA]
// -> sched_barrier -> [fold+gate+store L1] -> sched_barrier ->
// [fold+gate+store L2] -> one __syncthreads. L2 skewed one step.
// i8 16x16x64 limb scheme: W=(hi*256+lo)/260096, h=(hi*256+lo)/32512,
// lo offset-binary (hq^0x80, encoded zero 0x80), +128*rowsum(Whi)
// correction folded into integer acc-init (ones-MFMA at setup).
// exp2-domain gates; sigma byte-permute stores; integer DPP-fold
// (all-lanes-active call sites); k=0 peeled (enc-zero init exact).

#define TT 512
#define HH 64
#define BT 8

typedef __attribute__((ext_vector_type(4))) int i32x4;

#define MFMAI8 __builtin_amdgcn_mfma_i32_16x16x64_i8

#define WSCALE 260096.0f   /* 32512 / 0.125 */
#define HSCALE 32512.0f    /* |h| <= 1      */
#define LOG2E  1.44269504f
constexpr float C_SIG = (float)(256.0 / (260096.0 * 32512.0) * 1.4426950408889634);
constexpr float C_TGH = (float)(2.0 * 256.0 / (260096.0 * 32512.0) * 1.4426950408889634);

__device__ __forceinline__ float exp2_hw(float x) {
    float r; asm("v_exp_f32 %0, %1" : "=v"(r) : "v"(x)); return r;
}
__device__ __forceinline__ float exp2n_hw(float x) {
    float r; asm("v_exp_f32 %0, -%1" : "=v"(r) : "v"(x)); return r;
}
// inputs pre-scaled: p0,p1,p3 by log2e; p2 by 2*log2e. c stays in real units.
__device__ __forceinline__ float gate4s(float p0, float p1, float p2, float p3, float& c) {
    float gi = __builtin_amdgcn_rcpf(1.f + exp2n_hw(p0));
    float gf = __builtin_amdgcn_rcpf(1.f + exp2n_hw(p1));
    float gg = 1.f - 2.f * __builtin_amdgcn_rcpf(1.f + exp2_hw(p2));
    float go = __builtin_amdgcn_rcpf(1.f + exp2n_hw(p3));
    c = fmaf(gf, c, gi * gg);
    float tc = 1.f - 2.f * __builtin_amdgcn_rcpf(1.f + exp2_hw(c * (2.f * LOG2E)));
    return go * tc;
}
// lane i <- lane (i^8) within each row of 16 (row_ror:8, HW-verified r6).
// All 64 lanes active at every call site (enclosing branches wave-uniform).
__device__ __forceinline__ int dpp_ror8_i(int v) {
    return __builtin_amdgcn_update_dpp(v, v, 0x128, 0xF, 0xF, true);
}
// 16 fp32 weights of one row-quarter -> i8 hi/lo limb frags, sigma-permuted:
// byte b of reg r holds W[base + 4*b + r].
__device__ __forceinline__ void cvtW16(const float* __restrict__ p, i32x4& hi, i32x4& lo) {
    #pragma unroll
    for (int r = 0; r < 4; ++r) {
        int hw = 0, lw = 0;
        #pragma unroll
        for (int b = 0; b < 4; ++b) {
            int wq = (int)rintf(p[4 * b + r] * WSCALE);   // |wq| <= 32512
            int h8 = (wq + 128) >> 8;                     // [-127,127]
            int l8 = wq - (h8 << 8);                      // [-128,127]
            hw |= (h8 & 0xFF) << (8 * b);
            lw |= (l8 & 0xFF) << (8 * b);
        }
        hi[r] = hw; lo[r] = lw;
    }
}

__global__ __launch_bounds__(512, 2) void lstm_mfma(
    const float* __restrict__ x,
    const float* __restrict__ Wih0, const float* __restrict__ Whh0,
    const float* __restrict__ bih0, const float* __restrict__ bhh0,
    const float* __restrict__ Wih1, const float* __restrict__ Whh1,
    const float* __restrict__ bih1, const float* __restrict__ bhh1,
    const float* __restrict__ fcW, const float* __restrict__ fcb,
    float* __restrict__ out)
{
    __shared__ float xs[BT][TT + 1];                        // 16.4 KB
    // h limbs in i8 B-layout: [layer][buf][limb][row][byte];
    // byte jj of row holds unit u = (row>>4)*16 + sigma(jj). Lo-plane is
    // offset-binary (hq^0x80); encoded zero = 0x80. Rows n>=8 keep init
    // forever (phantom cols -> exact zeros for the DPP fold).
    __shared__ __align__(16) signed char aH[2][2][2][64][16];  // 8 KB
    __shared__ float hF[BT][HH + 1];
    __shared__ float fcw_s[HH];

    const int t    = threadIdx.x;     // 0..511
    const int lane = t & 63;
    const int v    = t >> 6;          // wave 0..7: owns tiles 2v, 2v+1
    const int b0   = blockIdx.x * BT;
    const int m    = lane & 15;       // A-row-within-tile AND D-col (=batch)
    const int q    = lane >> 4;       // quad
    const int ts   = m >> 3;          // tile-select within the pair
    const int bpk  = m & 7;           // this lane's batch
    const int j    = 4 * (2 * v + ts) + q;   // this lane's hidden unit

    // ---- stage x; init limb planes (hi=0, lo=0x80 = encoded zero) ----
    for (int i = t; i < BT * TT; i += 512)
        xs[i >> 9][i & (TT - 1)] = x[(size_t)(b0 + (i >> 9)) * TT + (i & (TT - 1))];
    {
        int* z = (int*)aH;
        for (int i = t; i < 2048; i += 512)
            z[i] = ((i >> 8) & 1) ? 0x80808080 : 0;   // 256 ints per limb plane
    }
    if (t < HH) fcw_s[t] = fcW[t];

    // ---- persistent A-frag weights (i8 limbs): tiles 2v,2v+1, 3 matrices ----
    // A-row m in tile ti -> gate-row rho = (m&3)*64 + 4*ti + (m>>2)
    i32x4 A0h[2], A0l[2], I1h[2], I1l[2], H1h[2], H1l[2];
    #pragma unroll
    for (int i = 0; i < 2; ++i) {
        const int rho = (m & 3) * 64 + 4 * (2 * v + i) + (m >> 2);
        cvtW16(Whh0 + rho * HH + q * 16, A0h[i], A0l[i]);
        cvtW16(Wih1 + rho * HH + q * 16, I1h[i], I1l[i]);
        cvtW16(Whh1 + rho * HH + q * 16, H1h[i], H1l[i]);
    }

    // ---- per-tile accumulator-init corrections: +128*rowsum(Whi) ----
    i32x4 corrA[2], corrB[2];
    {
        i32x4 ones; ones[0] = 0x01010101; ones[1] = 0x01010101;
        ones[2] = 0x01010101; ones[3] = 0x01010101;
        i32x4 zz = {0, 0, 0, 0};
        #pragma unroll
        for (int i = 0; i < 2; ++i) {
            i32x4 Sa = MFMAI8(A0h[i], ones, zz, 0, 0, 0);
            i32x4 Sb = MFMAI8(H1h[i], ones, MFMAI8(I1h[i], ones, zz, 0, 0, 0), 0, 0, 0);
            #pragma unroll
            for (int r = 0; r < 4; ++r) {
                corrA[i][r] = Sa[r] << 7;
                corrB[i][r] = Sb[r] << 7;
            }
        }
    }

    // ---- per-lane combine constants (pre-scaled into exp2 domain) ----
    float wxb[4], bia1[4], bia2[4];
    #pragma unroll
    for (int g = 0; g < 4; ++g) {
        const int r = g * 64 + j;
        const float sc = (g == 2) ? 2.f * LOG2E : LOG2E;
        wxb[g]  = Wih0[r] * sc;
        bia1[g] = (bih0[r] + bhh0[r]) * sc;
        bia2[g] = (bih1[r] + bhh1[r]) * sc;
    }
    // scatter target: row wl, byte wb = sigma(j&15)
    const int wl = ((j >> 4) << 4) + bpk;
    const int wb = ((j & 3) << 2) | ((j >> 2) & 3);
    float c1 = 0.f, c2 = 0.f;

    __syncthreads();

    // ---- peeled k=0: L1 only (h2(-1) stays encoded zero by init) ----
    {
        i32x4 bh1 = *(const i32x4*)&aH[0][0][0][lane][0];
        i32x4 bl1 = *(const i32x4*)&aH[0][0][1][lane][0];
        i32x4 aHH[2], aMD[2];
        #pragma unroll
        for (int i = 0; i < 2; ++i) {
            i32x4 z4 = {0, 0, 0, 0};
            aHH[i] = MFMAI8(A0h[i], bh1, z4, 0, 0, 0);
            aMD[i] = MFMAI8(A0l[i], bh1, MFMAI8(A0h[i], bl1, corrA[i], 0, 0, 0), 0, 0, 0);
        }
        float xb = xs[bpk][0];
        float pre[4];
        #pragma unroll
        for (int r = 0; r < 4; ++r) {
            int Pa = (aHH[0][r] << 8) + aMD[0][r];
            int Pb = (aHH[1][r] << 8) + aMD[1][r];
            int P  = Pa + dpp_ror8_i(Pb);
            const float Cr = (r == 2) ? C_TGH : C_SIG;
            pre[r] = fmaf((float)P, Cr, fmaf(wxb[r], xb, bia1[r]));
        }
        float h1v = gate4s(pre[0], pre[1], pre[2], pre[3], c1);
        int hq = __float_as_int(fmaf(h1v, HSCALE, 12582912.f)) - 0x4B400000;
        aH[0][1][0][wl][wb] = (signed char)(hq >> 8);
        aH[0][1][1][wl][wb] = (signed char)(hq ^ 0x80);
        __syncthreads();
    }

    // ---- main loop k=1..511: L1 computes h1(k); L2 computes h2(k-1) ----
    #pragma unroll 2
    for (int k = 1; k < TT; ++k) {
        const int p = k & 1, pn = p ^ 1;
        i32x4 bh1 = *(const i32x4*)&aH[0][p][0][lane][0];
        i32x4 bl1 = *(const i32x4*)&aH[0][p][1][lane][0];
        i32x4 bh2 = *(const i32x4*)&aH[1][p][0][lane][0];
        i32x4 bl2 = *(const i32x4*)&aH[1][p][1][lane][0];
        float xb = xs[bpk][k];

        // ---- issue ALL MFMAs first: L1 (completes first), then L2 ----
        i32x4 aHH[2], aMD[2], bHH[2], bMD[2];
        #pragma unroll
        for (int i = 0; i < 2; ++i) {
            i32x4 z4 = {0, 0, 0, 0};
            aHH[i] = MFMAI8(A0h[i], bh1, z4, 0, 0, 0);
            aMD[i] = MFMAI8(A0l[i], bh1, MFMAI8(A0h[i], bl1, corrA[i], 0, 0, 0), 0, 0, 0);
        }
        #pragma unroll
        for (int i = 0; i < 2; ++i) {
            i32x4 z4 = {0, 0, 0, 0};
            bHH[i] = MFMAI8(H1h[i], bh2, MFMAI8(I1h[i], bh1, z4, 0, 0, 0), 0, 0, 0);
            bMD[i] = MFMAI8(H1l[i], bh2,
                     MFMAI8(H1h[i], bl2,
                     MFMAI8(I1l[i], bh1,
                     MFMAI8(I1h[i], bl1, corrB[i], 0, 0, 0), 0, 0, 0), 0, 0, 0), 0, 0, 0);
        }
        __builtin_amdgcn_sched_barrier(0);   // pin: all MFMA issues precede folds

        // ---- L1 fold+gate+store: overlaps L2's MFMA execution ----
        {
            float pre[4];
            #pragma unroll
            for (int r = 0; r < 4; ++r) {
                int Pa = (aHH[0][r] << 8) + aMD[0][r];
                int Pb = (aHH[1][r] << 8) + aMD[1][r];
                int P  = Pa + dpp_ror8_i(Pb);
                const float Cr = (r == 2) ? C_TGH : C_SIG;
                pre[r] = fmaf((float)P, Cr, fmaf(wxb[r], xb, bia1[r]));
            }
            float h1v = gate4s(pre[0], pre[1], pre[2], pre[3], c1);
            int hq = __float_as_int(fmaf(h1v, HSCALE, 12582912.f)) - 0x4B400000;
            aH[0][pn][0][wl][wb] = (signed char)(hq >> 8);
            aH[0][pn][1][wl][wb] = (signed char)(hq ^ 0x80);
        }
        __builtin_amdgcn_sched_barrier(0);   // pin: L2 fold strictly after L1 work

        // ---- L2 fold+gate+store: h2(k-1) ----
        {
            float pre[4];
            #pragma unroll
            for (int r = 0; r < 4; ++r) {
                int Pc = (bHH[0][r] << 8) + bMD[0][r];
                int Pd = (bHH[1][r] << 8) + bMD[1][r];
                int P  = Pc + dpp_ror8_i(Pd);
                const float Cr = (r == 2) ? C_TGH : C_SIG;
                pre[r] = fmaf((float)P, Cr, bia2[r]);
            }
            float h2v = gate4s(pre[0], pre[1], pre[2], pre[3], c2);
            int hq = __float_as_int(fmaf(h2v, HSCALE, 12582912.f)) - 0x4B400000;
            aH[1][pn][0][wl][wb] = (signed char)(hq >> 8);
            aH[1][pn][1][wl][wb] = (signed char)(hq ^ 0x80);
        }
        __syncthreads();
    }

    // ---- epilogue: h2(TT-1) from h1(TT-1) and h2(TT-2) (both in buf 0) ----
    {
        i32x4 bh1 = *(const i32x4*)&aH[0][0][0][lane][0];
        i32x4 bl1 = *(const i32x4*)&aH[0][0][1][lane][0];
        i32x4 bh2 = *(const i32x4*)&aH[1][0][0][lane][0];
        i32x4 bl2 = *(const i32x4*)&aH[1][0][1][lane][0];
        i32x4 bHH[2], bMD[2];
        #pragma unroll
        for (int i = 0; i < 2; ++i) {
            i32x4 z4 = {0, 0, 0, 0};
            bHH[i] = MFMAI8(H1h[i], bh2, MFMAI8(I1h[i], bh1, z4, 0, 0, 0), 0, 0, 0);
            bMD[i] = MFMAI8(H1l[i], bh2,
                     MFMAI8(H1h[i], bl2,
                     MFMAI8(I1l[i], bh1,
                     MFMAI8(I1h[i], bl1, corrB[i], 0, 0, 0), 0, 0, 0), 0, 0, 0), 0, 0, 0);
        }
        float pre[4];
        #pragma unroll
        for (int r = 0; r < 4; ++r) {
            int Pc = (bHH[0][r] << 8) + bMD[0][r];
            int Pd = (bHH[1][r] << 8) + bMD[1][r];
            int P  = Pc + dpp_ror8_i(Pd);
            const float Cr = (r == 2) ? C_TGH : C_SIG;
            pre[r] = fmaf((float)P, Cr, bia2[r]);
        }
        float h2v = gate4s(pre[0], pre[1], pre[2], pre[3], c2);
        hF[bpk][j] = h2v;
    }
    __syncthreads();

    // ---- final FC: out[b] = fcW . h2(TT-1)[b] + fcb ----
    if (t < BT) {
        float s = fcb[0];
        #pragma unroll 8
        for (int jj = 0; jj < HH; ++jj)
            s = fmaf(hF[t][jj], fcw_s[jj], s);
        out[b0 + t] = s;
    }
}

extern "C" void kernel_launch(void* const* d_in, const int* in_sizes, int n_in,
                              void* d_out, int out_size, void* d_ws, size_t ws_size,
                              hipStream_t stream) {
    const float* x    = (const float*)d_in[0];
    const float* Wih0 = (const float*)d_in[1];
    const float* Whh0 = (const float*)d_in[2];
    const float* bih0 = (const float*)d_in[3];
    const float* bhh0 = (const float*)d_in[4];
    const float* Wih1 = (const float*)d_in[5];
    const float* Whh1 = (const float*)d_in[6];
    const float* bih1 = (const float*)d_in[7];
    const float* bhh1 = (const float*)d_in[8];
    const float* fcW  = (const float*)d_in[9];
    const float* fcb  = (const float*)d_in[10];
    float* out = (float*)d_out;

    lstm_mfma<<<dim3(2048 / BT), dim3(512), 0, stream>>>(
        x, Wih0, Whh0, bih0, bhh0, Wih1, Whh1, bih1, bhh1, fcW, fcb, out);
}